// Round 1
// baseline (71.355 us; speedup 1.0000x reference)
//
#include <hip/hip_runtime.h>
#include <math.h>

// Problem constants (reference: N=1024, D=128, tau=1, beta=1)
#define NN 1024
#define DD 128

typedef __bf16 bf16x8 __attribute__((ext_vector_type(8)));
typedef float  floatx4 __attribute__((ext_vector_type(4)));

// ws layout (bytes):
//   0        : bf16 matrices [3][1024][128]  (x, lp, aug)   = 786432
//   786432   : norms  [3][1024] f32                         = 12288
//   798720   : acc[0]=center partial, acc[1]=instance partial, acc[2]=block counter
#define WS_NORMS  786432
#define WS_ACC    798720

// ---------------- prep: fp32 -> bf16 + row norms + zero accumulators --------
// grid 768 x 256: one wave per row, 3*1024 rows total.
__global__ __launch_bounds__(256) void align_prep(
    const float* __restrict__ x, const float* __restrict__ lp,
    const float* __restrict__ aug, __bf16* __restrict__ mats,
    float* __restrict__ norms, float* __restrict__ acc)
{
    // zero the two float accumulators and the uint counter (0.0f == 0u bits)
    if (blockIdx.x == 0 && threadIdx.x < 3) acc[threadIdx.x] = 0.0f;

    const int w    = threadIdx.x >> 6;
    const int lane = threadIdx.x & 63;
    const int gw   = blockIdx.x * 4 + w;          // 0..3071
    const int a    = gw >> 10;                    // array 0..2
    const int r    = gw & 1023;                   // row
    const float* src = (a == 0 ? x : (a == 1 ? lp : aug)) + (size_t)r * DD + lane * 2;
    const float2 v = *(const float2*)src;
    float sq = v.x * v.x + v.y * v.y;
    union { __bf16 b[2]; unsigned u; } t;
    t.b[0] = (__bf16)v.x; t.b[1] = (__bf16)v.y;
    *(unsigned*)(mats + (size_t)a * (NN * DD) + (size_t)r * DD + lane * 2) = t.u;
#pragma unroll
    for (int m = 1; m < 64; m <<= 1) sq += __shfl_xor(sq, m);
    if (lane == 0) norms[a * NN + r] = sq;
}

// ---------------- fused pair + finalize -------------------------------------
// grid (64, 2), block 512 (8 waves). Each block owns 16 i-rows of one pair
// and iterates over ALL 1024 j columns, so it holds the complete softmax
// denominator. Block partial of sum_i (pos_i - log(den_i)) goes to a
// device-scope atomic; the last block to finish writes the 3 outputs.
// Wave w covers j = jt*128 + w*16, jt = 0..7.
__global__ __launch_bounds__(512) void align_pair_fused(
    const __bf16* __restrict__ mats, const float* __restrict__ norms,
    float* __restrict__ acc, float* __restrict__ out)
{
    const float SCALE = 0.08838834764831845f;  // 1/sqrt(128)
    const int bx = blockIdx.x;     // i-tile (16 rows)
    const int p  = blockIdx.y;     // 0: x vs lp, 1: x vs aug
    const __bf16* __restrict__ A = mats;                              // x
    const __bf16* __restrict__ B = mats + (size_t)(p ? 2 : 1) * (NN * DD);
    const float*  __restrict__ nx = norms;
    const float*  __restrict__ ny = norms + (p ? 2 : 1) * NN;

    const int i0   = bx * 16;
    const int tid  = threadIdx.x;
    const int w    = tid >> 6;     // 0..7
    const int lane = tid & 63;
    const int col  = lane & 15;
    const int quad = lane >> 4;

    // A fragments: row i0+col, k = c*32 + quad*8 + [0..7]
    const __bf16* arow = A + (size_t)(i0 + col) * DD + quad * 8;
    bf16x8 afrag[4];
#pragma unroll
    for (int c = 0; c < 4; ++c) afrag[c] = *(const bf16x8*)(arow + c * 32);
    // norms for this lane's 4 C-rows (row = quad*4 + r)
    const float4 nxr = *(const float4*)(nx + i0 + quad * 4);

    float denom[4] = {0.f, 0.f, 0.f, 0.f};
    float pos[4]   = {0.f, 0.f, 0.f, 0.f};

#pragma unroll 2
    for (int jt = 0; jt < 8; ++jt) {
        const int j0 = jt * 128 + w * 16;
        const __bf16* brow = B + (size_t)(j0 + col) * DD + quad * 8;
        bf16x8 bfrag[4];
#pragma unroll
        for (int c = 0; c < 4; ++c) bfrag[c] = *(const bf16x8*)(brow + c * 32);
        const float nyv = ny[j0 + col];   // norm of column j0+col

        floatx4 acc4 = {0.f, 0.f, 0.f, 0.f};
#pragma unroll
        for (int c = 0; c < 4; ++c)
            acc4 = __builtin_amdgcn_mfma_f32_16x16x32_bf16(afrag[c], bfrag[c], acc4, 0, 0, 0);

#pragma unroll
        for (int r = 0; r < 4; ++r) {
            const int row = quad * 4 + r;          // C: col=lane&15, row=quad*4+r
            float d2 = fmaf(-2.f, acc4[r], nxr[r] + nyv);
            d2 = fmaxf(d2, 0.f);
            const float dm = SCALE * sqrtf(d2);
            denom[r] += __expf(dm);
            if (j0 + col == i0 + row) pos[r] = dm;
        }
    }

    // reduce across the 16 cols of each quad group
#pragma unroll
    for (int r = 0; r < 4; ++r) {
#pragma unroll
        for (int m = 1; m < 16; m <<= 1) {
            denom[r] += __shfl_xor(denom[r], m);
            pos[r]   += __shfl_xor(pos[r], m);
        }
    }

    __shared__ float ld_den[8][16];
    __shared__ float ld_pos[8][16];
    if (col == 0) {
#pragma unroll
        for (int r = 0; r < 4; ++r) {
            ld_den[w][quad * 4 + r] = denom[r];
            ld_pos[w][quad * 4 + r] = pos[r];
        }
    }
    __syncthreads();

    // rows 0..15 of this tile: contrib_i = pos_i - log(den_i); sum over 16 rows
    float contrib = 0.f;
    if (tid < 16) {
        float den = 0.f, po = 0.f;
#pragma unroll
        for (int k = 0; k < 8; ++k) { den += ld_den[k][tid]; po += ld_pos[k][tid]; }
        contrib = po - __logf(den);
    }
    if (w == 0) {
#pragma unroll
        for (int m = 1; m < 16; m <<= 1) contrib += __shfl_xor(contrib, m);
    }
    if (tid == 0) {
        atomicAdd(&acc[p], contrib);
        __threadfence();
        const unsigned old = atomicAdd((unsigned*)(acc + 2), 1u);
        if (old == 127u) {            // last of the 128 blocks
            const float a  = atomicAdd(&acc[0], 0.0f);  // coherent read (returns old)
            const float b  = atomicAdd(&acc[1], 0.0f);
            const float inv = 1.0f / (float)NN;
            const float c  = a * inv;   // center alignment loss
            const float ia = b * inv;   // instance alignment loss
            out[0] = c + ia;
            out[1] = c;
            out[2] = ia;
        }
    }
}

extern "C" void kernel_launch(void* const* d_in, const int* in_sizes, int n_in,
                              void* d_out, int out_size, void* d_ws, size_t ws_size,
                              hipStream_t stream) {
    const float* x   = (const float*)d_in[0];
    const float* aug = (const float*)d_in[1];
    const float* lp  = (const float*)d_in[2];
    float* out       = (float*)d_out;

    char* ws = (char*)d_ws;
    __bf16* mats  = (__bf16*)ws;
    float*  norms = (float*)(ws + WS_NORMS);
    float*  acc   = (float*)(ws + WS_ACC);

    align_prep<<<768, 256, 0, stream>>>(x, lp, aug, mats, norms, acc);
    align_pair_fused<<<dim3(64, 2), 512, 0, stream>>>(mats, norms, acc, out);
}